// Round 1
// 169.734 us; speedup vs baseline: 1.0120x; 1.0120x over previous
//
#include <hip/hip_runtime.h>
#include <math.h>

// EnergyCoulomb: B=32, N=512, D=1024, H=512
// R11: 256x256 8-phase GEMM (T2/T3/T4/T5). 256 blocks (1/CU), 512 thr
//      (8 waves, 2m x 4n, per-wave 128x64), BK=64, 16 K-tiles, 128 KiB LDS
//      double-buffer. Per K-tile 4 phases: {stage-half-tiles || ds_read
//      quadrant frags -> s_barrier -> setprio(1) 16 MFMA setprio(0) ->
//      s_barrier}; single counted s_waitcnt vmcnt(0) per K-tile after the
//      last MFMA cluster (loads issued >=2 phases earlier -> hidden).
//      LDS geometry: per row (128 B line) chunk p holds logical chunk
//      p^(row&7) -> uniform 8 lanes/bank-group on ds_read_b128; achieved
//      via pre-swizzled global source addrs (gload_lds dest stays linear).
//      prep/coulomb logic unchanged (parts now 4 column-block partials).

typedef unsigned short u16;
typedef unsigned int u32;
typedef __bf16 bf16x8 __attribute__((ext_vector_type(8)));
typedef float f32x4 __attribute__((ext_vector_type(4)));

#define GK 1024
#define NT 16

#define GLOAD_LDS16(g, l) __builtin_amdgcn_global_load_lds( \
    (const __attribute__((address_space(1))) void*)(g),     \
    (__attribute__((address_space(3))) void*)(l), 16, 0, 0)

__device__ __forceinline__ u16 f2bf(float f) {
    u32 u = __float_as_uint(f);
    return (u16)((u + 0x7FFFu + ((u >> 16) & 1u)) >> 16);
}

__device__ __forceinline__ float ssp_f(float x) {
    return __logf(0.5f * (__expf(x) + 1.0f));
}

__device__ __forceinline__ float ssp_slow(float x) {
    return fmaxf(x, 0.0f) + log1pf(expf(-fabsf(x))) - 0.6931471805599453f;
}

// ---------------- prep: conv_a + conv_w + out zero (R3-verified) ------

__global__ __launch_bounds__(256) void prep(
    const float* __restrict__ rep, const float* __restrict__ W1,
    const float* __restrict__ Wc1, u16* __restrict__ Abf,
    u16* __restrict__ Btb, float* __restrict__ out)
{
    __shared__ float tile[32][33];
    const int blk = blockIdx.x;
    const int t = threadIdx.x;
    if (blk < 8192) {
        int i = (blk * 256 + t) * 8;
        float4 x = *(const float4*)(rep + i);
        float4 y = *(const float4*)(rep + i + 4);
        union { u16 h[8]; uint4 v; } o;
        o.h[0] = f2bf(x.x); o.h[1] = f2bf(x.y); o.h[2] = f2bf(x.z); o.h[3] = f2bf(x.w);
        o.h[4] = f2bf(y.x); o.h[5] = f2bf(y.y); o.h[6] = f2bf(y.z); o.h[7] = f2bf(y.w);
        *(uint4*)(Abf + i) = o.v;
        if (blk == 0 && t < 32) out[t] = 0.0f;
    } else {
        const int bb = blk - 8192;                  // 0..1023
        const int k0 = (bb & 31) * 32;
        const int n0 = (bb >> 5) * 32;              // 0..1023
        const float* src = (n0 < 512) ? W1 : Wc1;
        const int ns0 = (n0 < 512) ? n0 : n0 - 512;
#pragma unroll
        for (int j = 0; j < 4; j++) {
            int idx = j * 256 + t;
            int kl = idx >> 5, nl = idx & 31;
            tile[kl][nl] = src[(size_t)(k0 + kl) * 512 + ns0 + nl];
        }
        __syncthreads();
#pragma unroll
        for (int j = 0; j < 4; j++) {
            int idx = j * 256 + t;
            int nl = idx >> 5, kl = idx & 31;
            Btb[(size_t)(n0 + nl) * 1024 + k0 + kl] = f2bf(tile[kl][nl]);
        }
    }
}

// ---------------- bf16 MFMA GEMM: 256x256 tile, BK=64, 8-phase ----------------
// LDS per buf: A 2048 chunks of 16B (256 rows x 8 k-chunks) then B same.
//   chunk slot ci: row=ci>>3, phys p=ci&7, logical k-chunk c = p^(row&7).
//   stage: lane of instr (w,p2,h): ci=h*1024+(w*2+p2)*64+lane,
//   global elem off = row*GK + c*8 (pre-swizzled source, linear LDS dest).
//   frag read (row, kk, q): u16 idx = row*64 + ((kk*4+q)^(row&7))*8;
//   row&7 == lm&7 for all frag rows -> per-lane constant swizzle.

__global__ __launch_bounds__(512, 2) void gemm_mfma(
    const u16* __restrict__ A,    // [16384][1024] bf16
    const u16* __restrict__ Bt,   // [1024][1024] bf16
    const float* __restrict__ b1, const float* __restrict__ W2,
    const float* __restrict__ bc1, const float* __restrict__ Wc2,
    float* __restrict__ parts)    // [4][16384]
{
    __shared__ u16 smem[2][32768];                  // 128 KiB: [buf][A 16384 | B 16384]

    // XCD swizzle (256 blocks, 8 XCDs): co-locate the 4 same-bm blocks
    const int blk = blockIdx.x;                     // 0..255
    const int swz = ((blk & 7) << 5) | (blk >> 3);
    const int bm = swz >> 2;                        // 0..63
    const int bn = swz & 3;                         // 0..3
    const int tid = threadIdx.x;
    const int w = tid >> 6, lane = tid & 63;        // 8 waves
    const int wm = w & 1, wn = w >> 1;              // 2m x 4n
    const int lm = lane & 15, q = lane >> 4;

    f32x4 acc[8][4];
#pragma unroll
    for (int i = 0; i < 8; i++)
#pragma unroll
        for (int j = 0; j < 4; j++)
            acc[i][j] = (f32x4){0.0f, 0.0f, 0.0f, 0.0f};

    // staging global offsets (elements), shared A/B geometry
    int goff[2][2];
#pragma unroll
    for (int h = 0; h < 2; h++)
#pragma unroll
        for (int p2 = 0; p2 < 2; p2++) {
            int ci = h * 1024 + (w * 2 + p2) * 64 + lane;
            int row = ci >> 3;
            int c = (ci & 7) ^ (row & 7);
            goff[h][p2] = row * GK + c * 8;
        }

    // frag read offsets (u16 units)
    int arow[4], brow[2], aswz[2];
#pragma unroll
    for (int mi = 0; mi < 4; mi++) arow[mi] = (wm * 128 + mi * 16 + lm) * 64;
#pragma unroll
    for (int nj = 0; nj < 2; nj++) brow[nj] = (wn * 64 + nj * 16 + lm) * 64;
#pragma unroll
    for (int kk = 0; kk < 2; kk++) aswz[kk] = ((kk * 4 + q) ^ (lm & 7)) * 8;

    const u16* Ab = A + (size_t)bm * 256 * GK;
    const u16* Bb = Bt + (size_t)bn * 256 * GK;

#define STAGE_HT(G, RG, H) do {                                               \
    GLOAD_LDS16((G) + goff[H][0], &smem[nxt][(RG) + ((H) * 1024 + (w * 2 + 0) * 64) * 8]); \
    GLOAD_LDS16((G) + goff[H][1], &smem[nxt][(RG) + ((H) * 1024 + (w * 2 + 1) * 64) * 8]); \
} while (0)

#define READ_A(MH)                                                            \
    _Pragma("unroll") for (int mi = 0; mi < 4; mi++)                          \
    _Pragma("unroll") for (int kk = 0; kk < 2; kk++)                          \
        afr[mi][kk] = *(const bf16x8*)&smem[cur][arow[mi] + (MH) * 4096 + aswz[kk]];

#define READ_B(NH)                                                            \
    _Pragma("unroll") for (int nj = 0; nj < 2; nj++)                          \
    _Pragma("unroll") for (int kk = 0; kk < 2; kk++)                          \
        bfr2[nj][kk] = *(const bf16x8*)&smem[cur][16384 + brow[nj] + (NH) * 2048 + aswz[kk]];

#define MFMA_QUAD(MH, NH)                                                     \
    _Pragma("unroll") for (int kk = 0; kk < 2; kk++)                          \
    _Pragma("unroll") for (int mi = 0; mi < 4; mi++)                          \
    _Pragma("unroll") for (int nj = 0; nj < 2; nj++)                          \
        acc[(MH) * 4 + mi][(NH) * 2 + nj] = __builtin_amdgcn_mfma_f32_16x16x32_bf16( \
            afr[mi][kk], bfr2[nj][kk], acc[(MH) * 4 + mi][(NH) * 2 + nj], 0, 0, 0);

    // prologue: stage tile 0 into buf 0, full drain, publish
    {
        const int nxt = 0;
#pragma unroll
        for (int h = 0; h < 2; h++) {
            STAGE_HT(Ab, 0, h);
            STAGE_HT(Bb, 16384, h);
        }
    }
    asm volatile("s_waitcnt vmcnt(0)" ::: "memory");
    __builtin_amdgcn_s_barrier();

    bf16x8 afr[4][2], bfr2[2][2];

    for (int t = 0; t < NT; ++t) {
        const int cur = t & 1, nxt = cur ^ 1;
        const bool st = (t < NT - 1);
        const u16* gA = Ab + ((t + 1) & (NT - 1)) * 64;
        const u16* gB = Bb + ((t + 1) & (NT - 1)) * 64;

        // ---- phase 0: quadrant (0,0); stage A-half0 + B-half0 of tile t+1
        if (st) { STAGE_HT(gA, 0, 0); STAGE_HT(gB, 16384, 0); }
        READ_A(0); READ_B(0);
        __builtin_amdgcn_s_barrier();
        __builtin_amdgcn_s_setprio(1);
        MFMA_QUAD(0, 0);
        __builtin_amdgcn_s_setprio(0);
        __builtin_amdgcn_s_barrier();

        // ---- phase 1: quadrant (0,1); stage A-half1 + B-half1
        if (st) { STAGE_HT(gA, 0, 1); STAGE_HT(gB, 16384, 1); }
        READ_B(1);
        __builtin_amdgcn_s_barrier();
        __builtin_amdgcn_s_setprio(1);
        MFMA_QUAD(0, 1);
        __builtin_amdgcn_s_setprio(0);
        __builtin_amdgcn_s_barrier();

        // ---- phase 2: quadrant (1,1)
        READ_A(1);
        __builtin_amdgcn_s_barrier();
        __builtin_amdgcn_s_setprio(1);
        MFMA_QUAD(1, 1);
        __builtin_amdgcn_s_setprio(0);
        __builtin_amdgcn_s_barrier();

        // ---- phase 3: quadrant (1,0); publish tile t+1
        READ_B(0);
        __builtin_amdgcn_s_barrier();
        __builtin_amdgcn_s_setprio(1);
        MFMA_QUAD(1, 0);
        __builtin_amdgcn_s_setprio(0);
        if (st) asm volatile("s_waitcnt vmcnt(0)" ::: "memory");
        __builtin_amdgcn_s_barrier();
    }

#undef STAGE_HT
#undef READ_A
#undef READ_B
#undef MFMA_QUAD

    // epilogue: s = sum_nfr v[nfr]*ssp(acc+bias[nfr]); 16-lane shfl reduce;
    // cross-wave (wn) combine in LDS (aliased over smem); store to parts.
    __syncthreads();
    float* red = (float*)&smem[0][0];               // [4][256]
    const bool is_q = (bn >= 2);
    const float* bb2 = is_q ? bc1 : b1;
    const float* vv = is_q ? Wc2 : W2;
    float bias[4], v[4];
#pragma unroll
    for (int nfr = 0; nfr < 4; nfr++) {
        int c = (bn & 1) * 256 + wn * 64 + nfr * 16 + lm;
        bias[nfr] = bb2[c];
        v[nfr] = vv[c];
    }
#pragma unroll
    for (int mfr = 0; mfr < 8; mfr++) {
#pragma unroll
        for (int r = 0; r < 4; r++) {
            float s = 0.0f;
#pragma unroll
            for (int nfr = 0; nfr < 4; nfr++)
                s += v[nfr] * ssp_f(acc[mfr][nfr][r] + bias[nfr]);
            s += __shfl_xor(s, 1);
            s += __shfl_xor(s, 2);
            s += __shfl_xor(s, 4);
            s += __shfl_xor(s, 8);
            if (lm == 0) red[wn * 256 + wm * 128 + mfr * 16 + q * 4 + r] = s;
        }
    }
    __syncthreads();
    if (tid < 256) {
        float val = red[0 * 256 + tid] + red[1 * 256 + tid] +
                    red[2 * 256 + tid] + red[3 * 256 + tid];
        parts[(size_t)bn * 16384 + bm * 256 + tid] = val;
    }
}

// ---------------- coulomb: 256 blocks (8 chunks x 32 batches) ----------------

__global__ __launch_bounds__(256) void coulomb_k(
    const float* __restrict__ R, const float* __restrict__ mask,
    const float* __restrict__ parts, const float* __restrict__ b2p,
    const float* __restrict__ bc2p, float* __restrict__ out)
{
    const int N = 512;
    const int b = blockIdx.y;
    const int chunk = blockIdx.x;
    __shared__ float Rx[512], Ry[512], Rz[512], QM[512];
    __shared__ float rbuf[4];
    const int tid = threadIdx.x;
    const float bc2 = bc2p[0];
    const float b2 = b2p[0];

    for (int j = tid; j < N; j += 256) {
        int idx = b * N + j;
        float m = mask[idx];
        const float* rp = R + (size_t)idx * 3;
        Rx[j] = rp[0];
        Ry[j] = rp[1];
        Rz[j] = rp[2];
        float qv = parts[2 * 16384 + idx] + parts[3 * 16384 + idx] + bc2;
        QM[j] = qv * m;
    }
    __syncthreads();

    const int i = chunk * 64 + (tid & 63);
    const int js = (tid >> 6) * 128;
    const float xi = Rx[i], yi = Ry[i], zi = Rz[i], qmi = QM[i];
    float e = 0.0f;
    for (int j = js; j < js + 128; j++) {
        float dx = xi - Rx[j];
        float dy = yi - Ry[j];
        float dz = zi - Rz[j];
        float d2 = dx * dx + dy * dy + dz * dz;
        float t = 1e-5f + sqrtf(d2);
        float term = qmi * QM[j] / (t * t);
        e += (j == i) ? 0.0f : term;
    }
    if (tid < 64) {
        int ii = b * N + chunk * 64 + tid;
        float yv = parts[0 * 16384 + ii] + parts[1 * 16384 + ii] + b2;
        e += yv * mask[ii];
    }
    for (int off = 32; off > 0; off >>= 1) e += __shfl_down(e, off, 64);
    if ((tid & 63) == 0) rbuf[tid >> 6] = e;
    __syncthreads();
    if (tid == 0) atomicAdd(&out[b], rbuf[0] + rbuf[1] + rbuf[2] + rbuf[3]);
}

// ---------------- fp32 fallback (R1) ----------------

#define BM 128
#define BN 64
#define BK 16

__global__ __launch_bounds__(256) void mlp_gemm(
    const float* __restrict__ A, const float* __restrict__ W1,
    const float* __restrict__ Wc1, const float* __restrict__ b1,
    const float* __restrict__ bc1, const float* __restrict__ W2,
    const float* __restrict__ Wc2, float* __restrict__ yi_part,
    float* __restrict__ q_part)
{
    const int K = 1024;
    const int bm = blockIdx.x;
    const int bn = blockIdx.y;
    const bool is_q = (bn >= 8);
    const float* __restrict__ W = is_q ? Wc1 : W1;
    const int j0 = (bn & 7) * BN;

    __shared__ float As[BK][BM + 4];
    __shared__ float Bs[BK][BN + 4];
    __shared__ float red[BM];

    const int tid = threadIdx.x;
    const int tx = tid & 15;
    const int ty = tid >> 4;

    float acc[8][4];
#pragma unroll
    for (int r = 0; r < 8; r++)
#pragma unroll
        for (int c = 0; c < 4; c++) acc[r][c] = 0.0f;

    const int a_row = tid >> 2;
    const int a_k4 = (tid & 3) * 4;
    const float* Arow0 = A + (size_t)(bm * BM + a_row) * K;
    const float* Arow1 = Arow0 + (size_t)64 * K;
    const int w_k = tid >> 4;
    const int w_j = (tid & 15) * 4;

    for (int kt = 0; kt < K; kt += BK) {
        float4 av0 = *(const float4*)(Arow0 + kt + a_k4);
        float4 av1 = *(const float4*)(Arow1 + kt + a_k4);
        float4 wv = *(const float4*)(W + (size_t)(kt + w_k) * 512 + j0 + w_j);
        __syncthreads();
        As[a_k4 + 0][a_row] = av0.x;
        As[a_k4 + 1][a_row] = av0.y;
        As[a_k4 + 2][a_row] = av0.z;
        As[a_k4 + 3][a_row] = av0.w;
        As[a_k4 + 0][a_row + 64] = av1.x;
        As[a_k4 + 1][a_row + 64] = av1.y;
        As[a_k4 + 2][a_row + 64] = av1.z;
        As[a_k4 + 3][a_row + 64] = av1.w;
        *(float4*)&Bs[w_k][w_j] = wv;
        __syncthreads();
#pragma unroll
        for (int kk = 0; kk < BK; kk++) {
            float4 a0 = *(const float4*)&As[kk][ty * 8];
            float4 a1 = *(const float4*)&As[kk][ty * 8 + 4];
            float4 bv = *(const float4*)&Bs[kk][tx * 4];
            float ar[8] = {a0.x, a0.y, a0.z, a0.w, a1.x, a1.y, a1.z, a1.w};
            float bc[4] = {bv.x, bv.y, bv.z, bv.w};
#pragma unroll
            for (int r = 0; r < 8; r++)
#pragma unroll
                for (int c = 0; c < 4; c++)
                    acc[r][c] = fmaf(ar[r], bc[c], acc[r][c]);
        }
    }

    const float* bb = is_q ? bc1 : b1;
    const float* vv = is_q ? Wc2 : W2;
    float bias[4], v[4];
#pragma unroll
    for (int c = 0; c < 4; c++) {
        bias[c] = bb[j0 + tx * 4 + c];
        v[c] = vv[j0 + tx * 4 + c];
    }
    if (tid < BM) red[tid] = 0.0f;
    __syncthreads();
#pragma unroll
    for (int r = 0; r < 8; r++) {
        float s = 0.0f;
#pragma unroll
        for (int c = 0; c < 4; c++)
            s += v[c] * ssp_slow(acc[r][c] + bias[c]);
        atomicAdd(&red[ty * 8 + r], s);
    }
    __syncthreads();
    float* target = is_q ? q_part : yi_part;
    if (tid < BM) atomicAdd(&target[(size_t)bm * BM + tid], red[tid]);
}

__global__ __launch_bounds__(256) void coulomb_fb(
    const float* __restrict__ R, const float* __restrict__ mask,
    const float* __restrict__ yi_part, const float* __restrict__ q_part,
    const float* __restrict__ b2p, const float* __restrict__ bc2p,
    float* __restrict__ out)
{
    const int N = 512;
    const int b = blockIdx.y;
    const int chunk = blockIdx.x;
    __shared__ float Rx[512], Ry[512], Rz[512], QM[512];
    __shared__ float rbuf[4];
    const int tid = threadIdx.x;
    const float bc2 = bc2p[0];
    const float b2 = b2p[0];

    for (int j = tid; j < N; j += 256) {
        float m = mask[b * N + j];
        const float* rp = R + ((size_t)b * N + j) * 3;
        Rx[j] = rp[0];
        Ry[j] = rp[1];
        Rz[j] = rp[2];
        QM[j] = (q_part[b * N + j] + bc2) * m;
    }
    __syncthreads();

    const int i = chunk * 64 + (tid & 63);
    const int js = (tid >> 6) * 128;
    const float xi = Rx[i], yi = Ry[i], zi = Rz[i], qmi = QM[i];
    float e = 0.0f;
    for (int j = js; j < js + 128; j++) {
        float dx = xi - Rx[j];
        float dy = yi - Ry[j];
        float dz = zi - Rz[j];
        float d2 = dx * dx + dy * dy + dz * dz;
        float t = 1e-5f + sqrtf(d2);
        float term = qmi * QM[j] / (t * t);
        e += (j == i) ? 0.0f : term;
    }
    if (tid < 64) {
        int ii = chunk * 64 + tid;
        e += (yi_part[b * N + ii] + b2) * mask[b * N + ii];
    }
    for (int off = 32; off > 0; off >>= 1) e += __shfl_down(e, off, 64);
    if ((tid & 63) == 0) rbuf[tid >> 6] = e;
    __syncthreads();
    if (tid == 0) atomicAdd(&out[b], rbuf[0] + rbuf[1] + rbuf[2] + rbuf[3]);
}

// ---------------- launch ----------------

extern "C" void kernel_launch(void* const* d_in, const int* in_sizes, int n_in,
                              void* d_out, int out_size, void* d_ws, size_t ws_size,
                              hipStream_t stream) {
    const float* rep  = (const float*)d_in[0];
    const float* R    = (const float*)d_in[1];
    const float* mask = (const float*)d_in[2];
    const float* W1   = (const float*)d_in[3];
    const float* b1   = (const float*)d_in[4];
    const float* W2   = (const float*)d_in[5];
    const float* b2   = (const float*)d_in[6];
    const float* Wc1  = (const float*)d_in[7];
    const float* bc1  = (const float*)d_in[8];
    const float* Wc2  = (const float*)d_in[9];
    const float* bc2  = (const float*)d_in[10];
    float* out = (float*)d_out;

    const size_t szA = 16384ull * 1024 * 2;   // 32 MB bf16 A
    const size_t szB = 1024ull * 1024 * 2;    // 2 MB bf16 Bt
    const size_t szP = 8ull * 16384 * 4;      // partials (4 used)
    const size_t need = szA + szB + szP;

    if (ws_size >= need) {
        u16* Abf = (u16*)d_ws;
        u16* Btb = (u16*)((char*)d_ws + szA);
        float* parts = (float*)((char*)d_ws + szA + szB);

        prep<<<8192 + 1024, 256, 0, stream>>>(rep, W1, Wc1, Abf, Btb, out);
        gemm_mfma<<<256, 512, 0, stream>>>(Abf, Btb, b1, W2, bc1, Wc2, parts);
        coulomb_k<<<dim3(8, 32), 256, 0, stream>>>(R, mask, parts, b2, bc2, out);
    } else {
        float* yi_part = (float*)d_ws;
        float* q_part = yi_part + 16384;
        hipMemsetAsync(d_ws, 0, 2 * 16384 * sizeof(float), stream);
        hipMemsetAsync(d_out, 0, 32 * sizeof(float), stream);
        mlp_gemm<<<dim3(128, 16), 256, 0, stream>>>(rep, W1, Wc1, b1, bc1, W2, Wc2,
                                                    yi_part, q_part);
        coulomb_fb<<<dim3(8, 32), 256, 0, stream>>>(R, mask, yi_part, q_part, b2, bc2, out);
    }
}

// Round 2
// 166.138 us; speedup vs baseline: 1.0339x; 1.0216x over previous
//
#include <hip/hip_runtime.h>
#include <math.h>

// EnergyCoulomb: B=32, N=512, D=1024, H=512
// R12: 256x256 GEMM, BK=64, 16 K-tiles, 128 KiB LDS double-buffer.
//      Schedule rebuilt for LDS-read/MFMA overlap: ONE barrier per K-tile
//      (was 8), frag reads issued ahead of consuming MFMA quadrant,
//      B-half frags double-buffered (b0f/b1f), A frags single-set with
//      WAR-ordered overwrite after Q01 issues. Per-tile: stage 8 loads
//      (t+1) -> read B1 -> Q00 -> Q01 -> read A1 -> Q11 -> Q10 ->
//      vmcnt(0)+lgkmcnt(0)+barrier (publish nxt, license cur overwrite)
//      -> read next tile's A0/B0. Waves free-run within a tile so wave
//      skew covers intra-wave read latency (m114). LDS geometry (goff /
//      arow / brow / aswz, XOR-on-chunk swizzle) is IDENTICAL to the
//      R11 refcheck-verified kernel; only the schedule changed.
//      prep/coulomb unchanged.

typedef unsigned short u16;
typedef unsigned int u32;
typedef __bf16 bf16x8 __attribute__((ext_vector_type(8)));
typedef float f32x4 __attribute__((ext_vector_type(4)));

#define GK 1024
#define NT 16

#define GLOAD_LDS16(g, l) __builtin_amdgcn_global_load_lds( \
    (const __attribute__((address_space(1))) void*)(g),     \
    (__attribute__((address_space(3))) void*)(l), 16, 0, 0)

__device__ __forceinline__ u16 f2bf(float f) {
    u32 u = __float_as_uint(f);
    return (u16)((u + 0x7FFFu + ((u >> 16) & 1u)) >> 16);
}

__device__ __forceinline__ float ssp_f(float x) {
    return __logf(0.5f * (__expf(x) + 1.0f));
}

__device__ __forceinline__ float ssp_slow(float x) {
    return fmaxf(x, 0.0f) + log1pf(expf(-fabsf(x))) - 0.6931471805599453f;
}

// ---------------- prep: conv_a + conv_w + out zero (R3-verified) ------

__global__ __launch_bounds__(256) void prep(
    const float* __restrict__ rep, const float* __restrict__ W1,
    const float* __restrict__ Wc1, u16* __restrict__ Abf,
    u16* __restrict__ Btb, float* __restrict__ out)
{
    __shared__ float tile[32][33];
    const int blk = blockIdx.x;
    const int t = threadIdx.x;
    if (blk < 8192) {
        int i = (blk * 256 + t) * 8;
        float4 x = *(const float4*)(rep + i);
        float4 y = *(const float4*)(rep + i + 4);
        union { u16 h[8]; uint4 v; } o;
        o.h[0] = f2bf(x.x); o.h[1] = f2bf(x.y); o.h[2] = f2bf(x.z); o.h[3] = f2bf(x.w);
        o.h[4] = f2bf(y.x); o.h[5] = f2bf(y.y); o.h[6] = f2bf(y.z); o.h[7] = f2bf(y.w);
        *(uint4*)(Abf + i) = o.v;
        if (blk == 0 && t < 32) out[t] = 0.0f;
    } else {
        const int bb = blk - 8192;                  // 0..1023
        const int k0 = (bb & 31) * 32;
        const int n0 = (bb >> 5) * 32;              // 0..1023
        const float* src = (n0 < 512) ? W1 : Wc1;
        const int ns0 = (n0 < 512) ? n0 : n0 - 512;
#pragma unroll
        for (int j = 0; j < 4; j++) {
            int idx = j * 256 + t;
            int kl = idx >> 5, nl = idx & 31;
            tile[kl][nl] = src[(size_t)(k0 + kl) * 512 + ns0 + nl];
        }
        __syncthreads();
#pragma unroll
        for (int j = 0; j < 4; j++) {
            int idx = j * 256 + t;
            int nl = idx >> 5, kl = idx & 31;
            Btb[(size_t)(n0 + nl) * 1024 + k0 + kl] = f2bf(tile[kl][nl]);
        }
    }
}

// ---------------- bf16 MFMA GEMM: 256x256 tile, BK=64, overlap schedule ------

__global__ __launch_bounds__(512, 2) void gemm_mfma(
    const u16* __restrict__ A,    // [16384][1024] bf16
    const u16* __restrict__ Bt,   // [1024][1024] bf16
    const float* __restrict__ b1, const float* __restrict__ W2,
    const float* __restrict__ bc1, const float* __restrict__ Wc2,
    float* __restrict__ parts)    // [4][16384]
{
    __shared__ u16 smem[2][32768];                  // 128 KiB: [buf][A 16384 | B 16384]

    // XCD swizzle (256 blocks, 8 XCDs): co-locate the 4 same-bm blocks
    const int blk = blockIdx.x;                     // 0..255
    const int swz = ((blk & 7) << 5) | (blk >> 3);
    const int bm = swz >> 2;                        // 0..63
    const int bn = swz & 3;                         // 0..3
    const int tid = threadIdx.x;
    const int w = tid >> 6, lane = tid & 63;        // 8 waves
    const int wm = w & 1, wn = w >> 1;              // 2m x 4n
    const int lm = lane & 15, q = lane >> 4;

    f32x4 acc[8][4];
#pragma unroll
    for (int i = 0; i < 8; i++)
#pragma unroll
        for (int j = 0; j < 4; j++)
            acc[i][j] = (f32x4){0.0f, 0.0f, 0.0f, 0.0f};

    // staging global offsets (elements) — R11-verified geometry
    int goff[2][2];
#pragma unroll
    for (int h = 0; h < 2; h++)
#pragma unroll
        for (int p2 = 0; p2 < 2; p2++) {
            int ci = h * 1024 + (w * 2 + p2) * 64 + lane;
            int row = ci >> 3;
            int c = (ci & 7) ^ (row & 7);
            goff[h][p2] = row * GK + c * 8;
        }

    // frag read offsets (u16 units) — R11-verified geometry
    int arow[4], brow[2], aswz[2];
#pragma unroll
    for (int mi = 0; mi < 4; mi++) arow[mi] = (wm * 128 + mi * 16 + lm) * 64;
#pragma unroll
    for (int nj = 0; nj < 2; nj++) brow[nj] = (wn * 64 + nj * 16 + lm) * 64;
#pragma unroll
    for (int kk = 0; kk < 2; kk++) aswz[kk] = ((kk * 4 + q) ^ (lm & 7)) * 8;

    const u16* Ab = A + (size_t)bm * 256 * GK;
    const u16* Bb = Bt + (size_t)bn * 256 * GK;

#define STAGE_HT(G, RG, H, BUF) do {                                          \
    GLOAD_LDS16((G) + goff[H][0], &smem[BUF][(RG) + ((H) * 1024 + (w * 2 + 0) * 64) * 8]); \
    GLOAD_LDS16((G) + goff[H][1], &smem[BUF][(RG) + ((H) * 1024 + (w * 2 + 1) * 64) * 8]); \
} while (0)

#define READ_A(BUF, MH)                                                       \
    _Pragma("unroll") for (int mi = 0; mi < 4; mi++)                          \
    _Pragma("unroll") for (int kk = 0; kk < 2; kk++)                          \
        afr[mi][kk] = *(const bf16x8*)&smem[BUF][arow[mi] + (MH) * 4096 + aswz[kk]];

#define READ_B(BUF, NH, DST)                                                  \
    _Pragma("unroll") for (int nj = 0; nj < 2; nj++)                          \
    _Pragma("unroll") for (int kk = 0; kk < 2; kk++)                          \
        DST[nj][kk] = *(const bf16x8*)&smem[BUF][16384 + brow[nj] + (NH) * 2048 + aswz[kk]];

    // MFMA quadrant: afr must currently hold A-half MH; BF holds B-half NH
#define MFMA_QUAD(MH, NH, BF)                                                 \
    _Pragma("unroll") for (int kk = 0; kk < 2; kk++)                          \
    _Pragma("unroll") for (int mi = 0; mi < 4; mi++)                          \
    _Pragma("unroll") for (int nj = 0; nj < 2; nj++)                          \
        acc[(MH) * 4 + mi][(NH) * 2 + nj] = __builtin_amdgcn_mfma_f32_16x16x32_bf16( \
            afr[mi][kk], BF[nj][kk], acc[(MH) * 4 + mi][(NH) * 2 + nj], 0, 0, 0);

    // prologue: stage tile 0 into buf 0, drain, publish, preload Q0 frags
#pragma unroll
    for (int h = 0; h < 2; h++) {
        STAGE_HT(Ab, 0, h, 0);
        STAGE_HT(Bb, 16384, h, 0);
    }
    asm volatile("s_waitcnt vmcnt(0)" ::: "memory");
    __builtin_amdgcn_s_barrier();

    bf16x8 afr[4][2], b0f[2][2], b1f[2][2];
    READ_A(0, 0);
    READ_B(0, 0, b0f);

    for (int t = 0; t < NT; ++t) {
        const int cur = t & 1, nxt = cur ^ 1;
        const bool st = (t < NT - 1);
        const u16* gA = Ab + (t + 1) * 64;
        const u16* gB = Bb + (t + 1) * 64;

        // issue all 8 stage loads for tile t+1 into buf[nxt]
        if (st) {
            STAGE_HT(gA, 0, 0, nxt);
            STAGE_HT(gB, 16384, 0, nxt);
            STAGE_HT(gA, 0, 1, nxt);
            STAGE_HT(gB, 16384, 1, nxt);
        }

        // B-half1 frags ahead of Q01; Q00 runs on already-resident frags
        READ_B(cur, 1, b1f);
        __builtin_amdgcn_s_setprio(1);
        MFMA_QUAD(0, 0, b0f);
        MFMA_QUAD(0, 1, b1f);
        __builtin_amdgcn_s_setprio(0);

        // A-half1 overwrites afr (WAR after Q01 issues), ahead of Q11/Q10
        READ_A(cur, 1);
        __builtin_amdgcn_s_setprio(1);
        MFMA_QUAD(1, 1, b1f);
        MFMA_QUAD(1, 0, b0f);
        __builtin_amdgcn_s_setprio(0);

        // publish buf[nxt] (tile t+1) and license overwrite of buf[cur]:
        // own stage loads landed + own frag reads complete, then barrier.
        asm volatile("s_waitcnt vmcnt(0)" ::: "memory");
        asm volatile("s_waitcnt lgkmcnt(0)" ::: "memory");
        __builtin_amdgcn_s_barrier();

        // preload next tile's Q0 operands from the just-published buffer
        if (st) {
            READ_A(nxt, 0);
            READ_B(nxt, 0, b0f);
        }
    }

#undef STAGE_HT
#undef READ_A
#undef READ_B
#undef MFMA_QUAD

    // epilogue: s = sum_nfr v[nfr]*ssp(acc+bias[nfr]); 16-lane shfl reduce;
    // cross-wave (wn) combine in LDS (aliased over smem); store to parts.
    __syncthreads();
    float* red = (float*)&smem[0][0];               // [4][256]
    const bool is_q = (bn >= 2);
    const float* bb2 = is_q ? bc1 : b1;
    const float* vv = is_q ? Wc2 : W2;
    float bias[4], v[4];
#pragma unroll
    for (int nfr = 0; nfr < 4; nfr++) {
        int c = (bn & 1) * 256 + wn * 64 + nfr * 16 + lm;
        bias[nfr] = bb2[c];
        v[nfr] = vv[c];
    }
#pragma unroll
    for (int mfr = 0; mfr < 8; mfr++) {
#pragma unroll
        for (int r = 0; r < 4; r++) {
            float s = 0.0f;
#pragma unroll
            for (int nfr = 0; nfr < 4; nfr++)
                s += v[nfr] * ssp_f(acc[mfr][nfr][r] + bias[nfr]);
            s += __shfl_xor(s, 1);
            s += __shfl_xor(s, 2);
            s += __shfl_xor(s, 4);
            s += __shfl_xor(s, 8);
            if (lm == 0) red[wn * 256 + wm * 128 + mfr * 16 + q * 4 + r] = s;
        }
    }
    __syncthreads();
    if (tid < 256) {
        float val = red[0 * 256 + tid] + red[1 * 256 + tid] +
                    red[2 * 256 + tid] + red[3 * 256 + tid];
        parts[(size_t)bn * 16384 + bm * 256 + tid] = val;
    }
}

// ---------------- coulomb: 256 blocks (8 chunks x 32 batches) ----------------

__global__ __launch_bounds__(256) void coulomb_k(
    const float* __restrict__ R, const float* __restrict__ mask,
    const float* __restrict__ parts, const float* __restrict__ b2p,
    const float* __restrict__ bc2p, float* __restrict__ out)
{
    const int N = 512;
    const int b = blockIdx.y;
    const int chunk = blockIdx.x;
    __shared__ float Rx[512], Ry[512], Rz[512], QM[512];
    __shared__ float rbuf[4];
    const int tid = threadIdx.x;
    const float bc2 = bc2p[0];
    const float b2 = b2p[0];

    for (int j = tid; j < N; j += 256) {
        int idx = b * N + j;
        float m = mask[idx];
        const float* rp = R + (size_t)idx * 3;
        Rx[j] = rp[0];
        Ry[j] = rp[1];
        Rz[j] = rp[2];
        float qv = parts[2 * 16384 + idx] + parts[3 * 16384 + idx] + bc2;
        QM[j] = qv * m;
    }
    __syncthreads();

    const int i = chunk * 64 + (tid & 63);
    const int js = (tid >> 6) * 128;
    const float xi = Rx[i], yi = Ry[i], zi = Rz[i], qmi = QM[i];
    float e = 0.0f;
    for (int j = js; j < js + 128; j++) {
        float dx = xi - Rx[j];
        float dy = yi - Ry[j];
        float dz = zi - Rz[j];
        float d2 = dx * dx + dy * dy + dz * dz;
        float t = 1e-5f + sqrtf(d2);
        float term = qmi * QM[j] / (t * t);
        e += (j == i) ? 0.0f : term;
    }
    if (tid < 64) {
        int ii = b * N + chunk * 64 + tid;
        float yv = parts[0 * 16384 + ii] + parts[1 * 16384 + ii] + b2;
        e += yv * mask[ii];
    }
    for (int off = 32; off > 0; off >>= 1) e += __shfl_down(e, off, 64);
    if ((tid & 63) == 0) rbuf[tid >> 6] = e;
    __syncthreads();
    if (tid == 0) atomicAdd(&out[b], rbuf[0] + rbuf[1] + rbuf[2] + rbuf[3]);
}

// ---------------- fp32 fallback (R1) ----------------

#define BM 128
#define BN 64
#define BK 16

__global__ __launch_bounds__(256) void mlp_gemm(
    const float* __restrict__ A, const float* __restrict__ W1,
    const float* __restrict__ Wc1, const float* __restrict__ b1,
    const float* __restrict__ bc1, const float* __restrict__ W2,
    const float* __restrict__ Wc2, float* __restrict__ yi_part,
    float* __restrict__ q_part)
{
    const int K = 1024;
    const int bm = blockIdx.x;
    const int bn = blockIdx.y;
    const bool is_q = (bn >= 8);
    const float* __restrict__ W = is_q ? Wc1 : W1;
    const int j0 = (bn & 7) * BN;

    __shared__ float As[BK][BM + 4];
    __shared__ float Bs[BK][BN + 4];
    __shared__ float red[BM];

    const int tid = threadIdx.x;
    const int tx = tid & 15;
    const int ty = tid >> 4;

    float acc[8][4];
#pragma unroll
    for (int r = 0; r < 8; r++)
#pragma unroll
        for (int c = 0; c < 4; c++) acc[r][c] = 0.0f;

    const int a_row = tid >> 2;
    const int a_k4 = (tid & 3) * 4;
    const float* Arow0 = A + (size_t)(bm * BM + a_row) * K;
    const float* Arow1 = Arow0 + (size_t)64 * K;
    const int w_k = tid >> 4;
    const int w_j = (tid & 15) * 4;

    for (int kt = 0; kt < K; kt += BK) {
        float4 av0 = *(const float4*)(Arow0 + kt + a_k4);
        float4 av1 = *(const float4*)(Arow1 + kt + a_k4);
        float4 wv = *(const float4*)(W + (size_t)(kt + w_k) * 512 + j0 + w_j);
        __syncthreads();
        As[a_k4 + 0][a_row] = av0.x;
        As[a_k4 + 1][a_row] = av0.y;
        As[a_k4 + 2][a_row] = av0.z;
        As[a_k4 + 3][a_row] = av0.w;
        As[a_k4 + 0][a_row + 64] = av1.x;
        As[a_k4 + 1][a_row + 64] = av1.y;
        As[a_k4 + 2][a_row + 64] = av1.z;
        As[a_k4 + 3][a_row + 64] = av1.w;
        *(float4*)&Bs[w_k][w_j] = wv;
        __syncthreads();
#pragma unroll
        for (int kk = 0; kk < BK; kk++) {
            float4 a0 = *(const float4*)&As[kk][ty * 8];
            float4 a1 = *(const float4*)&As[kk][ty * 8 + 4];
            float4 bv = *(const float4*)&Bs[kk][tx * 4];
            float ar[8] = {a0.x, a0.y, a0.z, a0.w, a1.x, a1.y, a1.z, a1.w};
            float bc[4] = {bv.x, bv.y, bv.z, bv.w};
#pragma unroll
            for (int r = 0; r < 8; r++)
#pragma unroll
                for (int c = 0; c < 4; c++)
                    acc[r][c] = fmaf(ar[r], bc[c], acc[r][c]);
        }
    }

    const float* bb = is_q ? bc1 : b1;
    const float* vv = is_q ? Wc2 : W2;
    float bias[4], v[4];
#pragma unroll
    for (int c = 0; c < 4; c++) {
        bias[c] = bb[j0 + tx * 4 + c];
        v[c] = vv[j0 + tx * 4 + c];
    }
    if (tid < BM) red[tid] = 0.0f;
    __syncthreads();
#pragma unroll
    for (int r = 0; r < 8; r++) {
        float s = 0.0f;
#pragma unroll
        for (int c = 0; c < 4; c++)
            s += v[c] * ssp_slow(acc[r][c] + bias[c]);
        atomicAdd(&red[ty * 8 + r], s);
    }
    __syncthreads();
    float* target = is_q ? q_part : yi_part;
    if (tid < BM) atomicAdd(&target[(size_t)bm * BM + tid], red[tid]);
}

__global__ __launch_bounds__(256) void coulomb_fb(
    const float* __restrict__ R, const float* __restrict__ mask,
    const float* __restrict__ yi_part, const float* __restrict__ q_part,
    const float* __restrict__ b2p, const float* __restrict__ bc2p,
    float* __restrict__ out)
{
    const int N = 512;
    const int b = blockIdx.y;
    const int chunk = blockIdx.x;
    __shared__ float Rx[512], Ry[512], Rz[512], QM[512];
    __shared__ float rbuf[4];
    const int tid = threadIdx.x;
    const float bc2 = bc2p[0];
    const float b2 = b2p[0];

    for (int j = tid; j < N; j += 256) {
        float m = mask[b * N + j];
        const float* rp = R + ((size_t)b * N + j) * 3;
        Rx[j] = rp[0];
        Ry[j] = rp[1];
        Rz[j] = rp[2];
        QM[j] = (q_part[b * N + j] + bc2) * m;
    }
    __syncthreads();

    const int i = chunk * 64 + (tid & 63);
    const int js = (tid >> 6) * 128;
    const float xi = Rx[i], yi = Ry[i], zi = Rz[i], qmi = QM[i];
    float e = 0.0f;
    for (int j = js; j < js + 128; j++) {
        float dx = xi - Rx[j];
        float dy = yi - Ry[j];
        float dz = zi - Rz[j];
        float d2 = dx * dx + dy * dy + dz * dz;
        float t = 1e-5f + sqrtf(d2);
        float term = qmi * QM[j] / (t * t);
        e += (j == i) ? 0.0f : term;
    }
    if (tid < 64) {
        int ii = chunk * 64 + tid;
        e += (yi_part[b * N + ii] + b2) * mask[b * N + ii];
    }
    for (int off = 32; off > 0; off >>= 1) e += __shfl_down(e, off, 64);
    if ((tid & 63) == 0) rbuf[tid >> 6] = e;
    __syncthreads();
    if (tid == 0) atomicAdd(&out[b], rbuf[0] + rbuf[1] + rbuf[2] + rbuf[3]);
}

// ---------------- launch ----------------

extern "C" void kernel_launch(void* const* d_in, const int* in_sizes, int n_in,
                              void* d_out, int out_size, void* d_ws, size_t ws_size,
                              hipStream_t stream) {
    const float* rep  = (const float*)d_in[0];
    const float* R    = (const float*)d_in[1];
    const float* mask = (const float*)d_in[2];
    const float* W1   = (const float*)d_in[3];
    const float* b1   = (const float*)d_in[4];
    const float* W2   = (const float*)d_in[5];
    const float* b2   = (const float*)d_in[6];
    const float* Wc1  = (const float*)d_in[7];
    const float* bc1  = (const float*)d_in[8];
    const float* Wc2  = (const float*)d_in[9];
    const float* bc2  = (const float*)d_in[10];
    float* out = (float*)d_out;

    const size_t szA = 16384ull * 1024 * 2;   // 32 MB bf16 A
    const size_t szB = 1024ull * 1024 * 2;    // 2 MB bf16 Bt
    const size_t szP = 8ull * 16384 * 4;      // partials (4 used)
    const size_t need = szA + szB + szP;

    if (ws_size >= need) {
        u16* Abf = (u16*)d_ws;
        u16* Btb = (u16*)((char*)d_ws + szA);
        float* parts = (float*)((char*)d_ws + szA + szB);

        prep<<<8192 + 1024, 256, 0, stream>>>(rep, W1, Wc1, Abf, Btb, out);
        gemm_mfma<<<256, 512, 0, stream>>>(Abf, Btb, b1, W2, bc1, Wc2, parts);
        coulomb_k<<<dim3(8, 32), 256, 0, stream>>>(R, mask, parts, b2, bc2, out);
    } else {
        float* yi_part = (float*)d_ws;
        float* q_part = yi_part + 16384;
        hipMemsetAsync(d_ws, 0, 2 * 16384 * sizeof(float), stream);
        hipMemsetAsync(d_out, 0, 32 * sizeof(float), stream);
        mlp_gemm<<<dim3(128, 16), 256, 0, stream>>>(rep, W1, Wc1, b1, bc1, W2, Wc2,
                                                    yi_part, q_part);
        coulomb_fb<<<dim3(8, 32), 256, 0, stream>>>(R, mask, yi_part, q_part, b2, bc2, out);
    }
}